// Round 8
// baseline (279.714 us; speedup 1.0000x reference)
//
#include <hip/hip_runtime.h>
#include <math.h>

constexpr int Cc = 3, Hh = 256;
constexpr int NX = 393216;   // 2*3*256*256
constexpr int R = 8;         // rows per block
constexpr int NBLK = 192;    // 6 images * 32 tiles (<= 256 CUs: 1 block/CU)
constexpr int KSTEPS = 50;
constexpr int NSLOT = 3;

using u64 = unsigned long long;
constexpr u64 SENT = 0x8000000080000000ull;  // (-0.0f,-0.0f) pair: unreachable payload

__device__ __forceinline__ float4 ld4(const float* p, int i) { return ((const float4*)p)[i]; }
__device__ __forceinline__ void st4(float* p, int i, float4 v) { ((float4*)p)[i] = v; }
__device__ __forceinline__ float4 mk4(float a, float b, float c, float d) { return make_float4(a, b, c, d); }

__device__ __forceinline__ u64 ldq(const u64* p) {
    return __hip_atomic_load(p, __ATOMIC_RELAXED, __HIP_MEMORY_SCOPE_AGENT);
}
__device__ __forceinline__ void stq(u64* p, u64 v) {
    __hip_atomic_store(p, v, __ATOMIC_RELAXED, __HIP_MEMORY_SCOPE_AGENT);
}
__device__ __forceinline__ void pub4(u64* w, float4 v) {
    union { float f[2]; u64 q; } a, b;
    a.f[0] = v.x; a.f[1] = v.y; b.f[0] = v.z; b.f[1] = v.w;
    stq(w, a.q); stq(w + 1, b.q);
}
__device__ __forceinline__ float4 unp(u64 lo, u64 hi) {
    union { u64 q; float f[2]; } a, b; a.q = lo; b.q = hi;
    return make_float4(a.f[0], a.f[1], b.f[0], b.f[1]);
}
// H layout: u64 H[NSLOT][NBLK][4][128]; rows: 0=v0 last, 1=v0 first, 2=v1 first, 3=x first
__device__ __forceinline__ u64* recq(u64* H, int slot, int blk, int row) {
    return H + ((((size_t)slot * NBLK + blk) * 4 + row) << 7);
}

__global__ void init_ws(u64* H, u64* parts) {
    int i = blockIdx.x * 256 + threadIdx.x;
    if (i < NSLOT * NBLK * 4 * 128) H[i] = SENT;
    if (i < KSTEPS * NBLK) parts[i] = SENT;
}

__global__ void __launch_bounds__(256) cp_persist(
    const float* __restrict__ y, const float* __restrict__ lambd,
    float* __restrict__ xout, float* __restrict__ xtout, float* __restrict__ uout,
    u64* __restrict__ H, u64* __restrict__ parts)
{
    __shared__ float sxt[9 * 256];
    __shared__ float sv0[8 * 256];
    __shared__ float2 pw[4];
    const int tid = threadIdx.x;
    const int blk = blockIdx.x;
    const int bc = blk >> 5;           // image index [0,6)
    const int tile = blk & 31;         // [0,32)
    const int r0 = tile * R;
    const int c4 = tid & 63;
    const int trow = tid >> 6;         // [0,4)
    const int b = (bc >= Cc) ? 1 : 0;

    const float lamb = expf(lambd[0]);

    float4 yv[2], xreg[2], v0[2], v1[2], u0[2], u1[2], xtp[2];
    float4 yhalo = mk4(0.f, 0.f, 0.f, 0.f);
    if (trow == 0 && tile < 31) yhalo = ld4(y, bc * 16384 + (r0 + 8) * 64 + c4);

    // ---------------- init (iteration 0): x=y, v = nabla(y) ----------------
    {
        float pa0 = 0.f, pa1 = 0.f;
        #pragma unroll
        for (int k = 0; k < 2; ++k) {
            const int rr = trow + 4 * k;
            const int gh = r0 + rr;
            const int j4 = bc * 16384 + gh * 64 + c4;
            yv[k] = ld4(y, j4);
            xreg[k] = yv[k];
            float4 dh = mk4(0.f, 0.f, 0.f, 0.f);
            if (gh < Hh - 1) {
                float4 yn = ld4(y, j4 + 64);
                dh.x = yn.x - yv[k].x; dh.y = yn.y - yv[k].y;
                dh.z = yn.z - yv[k].z; dh.w = yn.w - yv[k].w;
            }
            float4 dw;
            dw.x = yv[k].y - yv[k].x; dw.y = yv[k].z - yv[k].y; dw.z = yv[k].w - yv[k].z;
            float ynx = __shfl_down(yv[k].x, 1, 64);
            dw.w = (c4 < 63) ? (ynx - yv[k].w) : 0.f;
            v0[k] = dh; v1[k] = dw;
            ((float4*)(sv0 + rr * 256))[c4] = dh;
            pa0 += dh.x*dh.x + dh.y*dh.y + dh.z*dh.z + dh.w*dh.w;
            pa1 += dw.x*dw.x + dw.y*dw.y + dw.z*dw.z + dw.w*dw.w;
        }
        if (trow == 0) {
            pub4(recq(H, 0, blk, 1) + 2 * c4, v0[0]);
            pub4(recq(H, 0, blk, 2) + 2 * c4, v1[0]);
            pub4(recq(H, 0, blk, 3) + 2 * c4, xreg[0]);
        }
        if (trow == 3) pub4(recq(H, 0, blk, 0) + 2 * c4, v0[1]);   // row r0+7
        #pragma unroll
        for (int m = 1; m < 64; m <<= 1) {
            pa0 += __shfl_xor(pa0, m, 64);
            pa1 += __shfl_xor(pa1, m, 64);
        }
        if (c4 == 0) pw[trow] = make_float2(pa0, pa1);
        asm volatile("s_waitcnt vmcnt(0)" ::: "memory");   // drain halo pubs (per wave)
        __syncthreads();                                    // all waves drained + pw visible
        if (tid == 0) {
            union { float f[2]; u64 q; } pk;
            pk.f[0] = pw[0].x + pw[1].x + pw[2].x + pw[3].x;
            pk.f[1] = pw[0].y + pw[1].y + pw[2].y + pw[3].y;
            stq(parts + blk, pk.q);
        }
    }

    float sigma = 0.20412414523193150818f;   // 0.5/sqrt(6)
    float tau   = sigma;

    for (int s = 1; s <= KSTEPS; ++s) {
        const int p = (s - 1) % NSLOT;
        const u64* pb = parts + (size_t)(s - 1) * NBLK;
        u64 t0, t1, t2;
        float4 vmtop = mk4(0.f, 0.f, 0.f, 0.f);
        float4 v0h = vmtop, v1h = vmtop, xoh = vmtop;

        // ------- merged poll: parts (all waves) + own halo words (wave 0) -------
        if (trow == 0) {
            const u64* rm = recq(H, p, blk - 1, 0) + 2 * c4;   // used only if tile>0
            const u64* r1 = recq(H, p, blk + 1, 1) + 2 * c4;   // used only if tile<31
            const u64* r2 = recq(H, p, blk + 1, 2) + 2 * c4;
            const u64* r3 = recq(H, p, blk + 1, 3) + 2 * c4;
            u64 m0 = SENT, m1 = SENT, h0 = SENT, h1 = SENT, h2 = SENT, h3 = SENT, h4 = SENT, h5 = SENT;
            for (;;) {
                t0 = ldq(pb + c4); t1 = ldq(pb + c4 + 64); t2 = ldq(pb + c4 + 128);
                bool ok = (t0 != SENT) && (t1 != SENT) && (t2 != SENT);
                if (tile > 0) {
                    m0 = ldq(rm); m1 = ldq(rm + 1);
                    ok = ok && (m0 != SENT) && (m1 != SENT);
                }
                if (tile < 31) {
                    h0 = ldq(r1); h1 = ldq(r1 + 1);
                    h2 = ldq(r2); h3 = ldq(r2 + 1);
                    h4 = ldq(r3); h5 = ldq(r3 + 1);
                    ok = ok && (h0 != SENT) && (h1 != SENT) && (h2 != SENT)
                            && (h3 != SENT) && (h4 != SENT) && (h5 != SENT);
                }
                if (__all(ok)) break;
                __builtin_amdgcn_s_sleep(1);
            }
            if (tile > 0)  vmtop = unp(m0, m1);
            if (tile < 31) { v0h = unp(h0, h1); v1h = unp(h2, h3); xoh = unp(h4, h5); }
        } else {
            for (;;) {
                t0 = ldq(pb + c4); t1 = ldq(pb + c4 + 64); t2 = ldq(pb + c4 + 128);
                if (__all((t0 != SENT) && (t1 != SENT) && (t2 != SENT))) break;
                __builtin_amdgcn_s_sleep(1);
            }
        }
        asm volatile("" ::: "memory");

        // ------- reset own record in slot (s+1)%3 (holds record s-2, provably dead) -------
        if (s < KSTEPS) {
            u64* rb = recq(H, (s + 1) % NSLOT, blk, 0);
            stq(rb + tid, SENT);
            stq(rb + tid + 256, SENT);
        }

        // scales: group-sum the polled payloads (fixed order + butterfly; deterministic)
        float g0 = 0.f, g1 = 0.f, g2 = 0.f, g3 = 0.f;
        {
            union { u64 q; float f[2]; } a0, a1, a2;
            a0.q = t0; a1.q = t1; a2.q = t2;
            g0 += a0.f[0]; g1 += a0.f[1];
            if (c4 < 32) { g0 += a1.f[0]; g1 += a1.f[1]; }
            else         { g2 += a1.f[0]; g3 += a1.f[1]; }
            g2 += a2.f[0]; g3 += a2.f[1];
            #pragma unroll
            for (int m = 1; m < 64; m <<= 1) {
                g0 += __shfl_xor(g0, m, 64);
                g1 += __shfl_xor(g1, m, 64);
                g2 += __shfl_xor(g2, m, 64);
                g3 += __shfl_xor(g3, m, 64);
            }
        }
        const float s0 = lamb / fmaxf(sqrtf(b ? g2 : g0), lamb);
        const float s1 = lamb / fmaxf(sqrtf(b ? g3 : g1), lamb);
        const float chi = 1.0f / sqrtf(1.0f + tau);
        const float inv = 1.0f / (1.0f + tau);
        const float opc = 1.0f + chi;
        const int q = s % NSLOT;

        // ---------------- phase B (step s-1) ----------------
        #pragma unroll
        for (int k = 0; k < 2; ++k) {
            const int rr = trow + 4 * k;
            const int gh = r0 + rr;
            float4 uu0, uu1;
            uu0.x = v0[k].x*s0; uu0.y = v0[k].y*s0; uu0.z = v0[k].z*s0; uu0.w = v0[k].w*s0;
            uu1.x = v1[k].x*s1; uu1.y = v1[k].y*s1; uu1.z = v1[k].z*s1; uu1.w = v1[k].w*s1;
            float4 vm = (k == 0) ? ((trow > 0) ? ((float4*)(sv0 + (trow - 1) * 256))[c4] : vmtop)
                                 : ((float4*)(sv0 + (trow + 3) * 256))[c4];
            float nt0 = 0.f, nt1 = 0.f, nt2 = 0.f, nt3 = 0.f;
            if (gh > 0) { nt0 += vm.x*s0; nt1 += vm.y*s0; nt2 += vm.z*s0; nt3 += vm.w*s0; }
            if (gh < Hh - 1) { nt0 -= uu0.x; nt1 -= uu0.y; nt2 -= uu0.z; nt3 -= uu0.w; }
            float ul = __shfl_up(uu1.w, 1, 64);
            if (c4 > 0) nt0 += ul;
            nt1 += uu1.x; nt2 += uu1.y; nt3 += uu1.z;
            nt0 -= uu1.x; nt1 -= uu1.y; nt2 -= uu1.z;
            if (c4 < 63) nt3 -= uu1.w;
            float4 xp;
            xp.x = (xreg[k].x + tau * (yv[k].x - nt0)) * inv;
            xp.y = (xreg[k].y + tau * (yv[k].y - nt1)) * inv;
            xp.z = (xreg[k].z + tau * (yv[k].z - nt2)) * inv;
            xp.w = (xreg[k].w + tau * (yv[k].w - nt3)) * inv;
            xtp[k].x = opc * xp.x - chi * xreg[k].x;
            xtp[k].y = opc * xp.y - chi * xreg[k].y;
            xtp[k].z = opc * xp.z - chi * xreg[k].z;
            xtp[k].w = opc * xp.w - chi * xreg[k].w;
            u0[k] = uu0; u1[k] = uu1;
            if (s == KSTEPS) {
                const int j4 = bc * 16384 + gh * 64 + c4;
                const int iv4 = bc * 32768 + gh * 64 + c4;
                st4(xout, j4, xp);
                st4(xtout, j4, xtp[k]);
                st4(uout, iv4, uu0);
                st4(uout, iv4 + 16384, uu1);
            } else {
                xreg[k] = xp;
                if (rr >= 1) ((float4*)(sxt + rr * 256))[c4] = xtp[k];
                if (trow == 0 && k == 0) pub4(recq(H, q, blk, 3) + 2 * c4, xp);
            }
        }
        if (s == KSTEPS) break;

        // ---- redundant halo row r0+8 (wave 0, tile<31; always interior in h) ----
        if (trow == 0 && tile < 31) {
            float4 h0, h1;
            h0.x = v0h.x*s0; h0.y = v0h.y*s0; h0.z = v0h.z*s0; h0.w = v0h.w*s0;
            h1.x = v1h.x*s1; h1.y = v1h.y*s1; h1.z = v1h.z*s1; h1.w = v1h.w*s1;
            float4 vmh = ((float4*)(sv0 + 7 * 256))[c4];
            float nt0 = vmh.x*s0 - h0.x, nt1 = vmh.y*s0 - h0.y,
                  nt2 = vmh.z*s0 - h0.z, nt3 = vmh.w*s0 - h0.w;
            float hul = __shfl_up(h1.w, 1, 64);
            if (c4 > 0) nt0 += hul;
            nt1 += h1.x; nt2 += h1.y; nt3 += h1.z;
            nt0 -= h1.x; nt1 -= h1.y; nt2 -= h1.z;
            if (c4 < 63) nt3 -= h1.w;
            float4 xph, xth;
            xph.x = (xoh.x + tau * (yhalo.x - nt0)) * inv;
            xph.y = (xoh.y + tau * (yhalo.y - nt1)) * inv;
            xph.z = (xoh.z + tau * (yhalo.z - nt2)) * inv;
            xph.w = (xoh.w + tau * (yhalo.w - nt3)) * inv;
            xth.x = opc * xph.x - chi * xoh.x;
            xth.y = opc * xph.y - chi * xoh.y;
            xth.z = opc * xph.z - chi * xoh.z;
            xth.w = opc * xph.w - chi * xoh.w;
            ((float4*)(sxt + 8 * 256))[c4] = xth;
        }
        __syncthreads();

        // ---------------- phase A (step s) ----------------
        const float sigs = sigma / chi;
        float pa0 = 0.f, pa1 = 0.f;
        #pragma unroll
        for (int k = 0; k < 2; ++k) {
            const int rr = trow + 4 * k;
            const int gh = r0 + rr;
            float4 dh = mk4(0.f, 0.f, 0.f, 0.f);
            if (gh < Hh - 1) {
                float4 xn = ((const float4*)(sxt + (rr + 1) * 256))[c4];
                dh.x = xn.x - xtp[k].x; dh.y = xn.y - xtp[k].y;
                dh.z = xn.z - xtp[k].z; dh.w = xn.w - xtp[k].w;
            }
            float4 dw;
            dw.x = xtp[k].y - xtp[k].x; dw.y = xtp[k].z - xtp[k].y; dw.z = xtp[k].w - xtp[k].z;
            float xnx = __shfl_down(xtp[k].x, 1, 64);
            dw.w = (c4 < 63) ? (xnx - xtp[k].w) : 0.f;
            v0[k].x = fmaf(sigs, dh.x, u0[k].x); v0[k].y = fmaf(sigs, dh.y, u0[k].y);
            v0[k].z = fmaf(sigs, dh.z, u0[k].z); v0[k].w = fmaf(sigs, dh.w, u0[k].w);
            v1[k].x = fmaf(sigs, dw.x, u1[k].x); v1[k].y = fmaf(sigs, dw.y, u1[k].y);
            v1[k].z = fmaf(sigs, dw.z, u1[k].z); v1[k].w = fmaf(sigs, dw.w, u1[k].w);
            ((float4*)(sv0 + rr * 256))[c4] = v0[k];
            pa0 += v0[k].x*v0[k].x + v0[k].y*v0[k].y + v0[k].z*v0[k].z + v0[k].w*v0[k].w;
            pa1 += v1[k].x*v1[k].x + v1[k].y*v1[k].y + v1[k].z*v1[k].z + v1[k].w*v1[k].w;
            if (trow == 0 && k == 0) {
                pub4(recq(H, q, blk, 1) + 2 * c4, v0[0]);
                pub4(recq(H, q, blk, 2) + 2 * c4, v1[0]);
            }
            if (trow == 3 && k == 1) pub4(recq(H, q, blk, 0) + 2 * c4, v0[1]);
        }
        #pragma unroll
        for (int m = 1; m < 64; m <<= 1) {
            pa0 += __shfl_xor(pa0, m, 64);
            pa1 += __shfl_xor(pa1, m, 64);
        }
        if (c4 == 0) pw[trow] = make_float2(pa0, pa1);
        asm volatile("s_waitcnt vmcnt(0)" ::: "memory");   // drain pubs+resets (per wave)
        __syncthreads();                                    // all waves drained + pw visible
        if (tid == 0) {
            union { float f[2]; u64 q; } pk;
            pk.f[0] = pw[0].x + pw[1].x + pw[2].x + pw[3].x;
            pk.f[1] = pw[0].y + pw[1].y + pw[2].y + pw[3].y;
            stq(parts + (size_t)s * NBLK + blk, pk.q);
        }

        tau *= chi;
        sigma = sigs;
    }
}

extern "C" void kernel_launch(void* const* d_in, const int* in_sizes, int n_in,
                              void* d_out, int out_size, void* d_ws, size_t ws_size,
                              hipStream_t stream) {
    (void)in_sizes; (void)n_in; (void)out_size; (void)ws_size;
    const float* y     = (const float*)d_in[0];
    const float* lambd = (const float*)d_in[1];
    float* xout  = (float*)d_out;       // [0, NX)
    float* xtout = xout + NX;           // [NX, 2NX)
    float* uout  = xout + 2 * NX;       // [2NX, 2NX+NU)

    u64* H     = (u64*)d_ws;                        // [NSLOT][NBLK][4][128] u64
    u64* parts = H + (size_t)NSLOT * NBLK * 4 * 128; // [KSTEPS][NBLK] u64

    init_ws<<<(NSLOT * NBLK * 4 * 128 + 255) / 256, 256, 0, stream>>>(H, parts);
    cp_persist<<<NBLK, 256, 0, stream>>>(y, lambd, xout, xtout, uout, H, parts);
}